// Round 7
// baseline (837745.703 us; speedup 1.0000x reference)
//
#include <hip/hip_runtime.h>
#include <stdint.h>

// RNNLayer: h_t = tanh([x_t, h_{t-1}] @ W + b), outputs all h_t [B,T,H] fp32.
// B=64, T=1024, D=1024, H=1024.  W: [D+H, H] fp32.
//
// Phase 1: XP = x @ W[:D] + b -> d_out (bf16 MFMA, 128x128 tiles).
// Phase 2: persistent scan, 4 rings x 8 WGs, 512 thr/WG, 16 rows x 128 cols each.
//   Rounds 4/5 were bound by the serial IF-coherent RTT (~7us/step, traffic-
//   and WG-count-independent). Rings are formed DYNAMICALLY on a single XCD
//   (s_getreg XCC_ID + registration + rendezvous), so the h exchange goes
//   through the SHARED PER-XCD L2: plain stores (L1 write-through) + sc0
//   loads (L1 bypass) ~= 90ns RTT instead of IF. Tags {step:16|bf16:16} keep
//   correctness placement-independent. Liveness insurance: per-thread sticky
//   degraded mode (timeout -> republish + agent sc1 exchange = round-5
//   semantics). One barrier/step via double-buffered A_lds.
//   Round-7 fix: s_sleep takes a LITERAL constant -> branch to constant calls.

#define T_LEN 1024
#define HID   1024
#define SCAN_WGS 256

typedef float    f32x4  __attribute__((ext_vector_type(4)));
typedef unsigned u32x4  __attribute__((ext_vector_type(4)));
typedef __bf16   bf16x8 __attribute__((ext_vector_type(8)));
typedef unsigned long long u64;

// ---------------- Phase 1: x_proj GEMM ----------------
__global__ __launch_bounds__(256) void xproj_gemm(
    const float* __restrict__ x, const float* __restrict__ W,
    const float* __restrict__ bias, float* __restrict__ out)
{
    __shared__ __align__(16) __bf16 As[128][40];
    __shared__ __align__(16) __bf16 Bs[128][40];

    const int bid = blockIdx.x;
    const int n0  = (bid & 7) << 7;
    const int64_t r0 = (int64_t)(bid >> 3) << 7;
    const int tid  = threadIdx.x;
    const int lane = tid & 63;
    const int w    = tid >> 6;
    const int hi   = lane >> 4, lo = lane & 15;
    const int wm   = (w >> 1) << 6, wn = (w & 1) << 6;

    f32x4 acc[4][4] = {};

    const int arow = tid >> 1, akh = (tid & 1) << 4;
    const int bk   = tid >> 3, bnh = (tid & 7) << 4;

    for (int k0 = 0; k0 < 1024; k0 += 32) {
        {
            const float* src = x + (r0 + arow) * 1024 + k0 + akh;
            bf16x8 t0, t1;
            #pragma unroll
            for (int i2 = 0; i2 < 8; ++i2) { t0[i2] = (__bf16)src[i2]; t1[i2] = (__bf16)src[8 + i2]; }
            *(bf16x8*)&As[arow][akh]     = t0;
            *(bf16x8*)&As[arow][akh + 8] = t1;
        }
        {
            const float* src = W + (int64_t)(k0 + bk) * 1024 + n0 + bnh;
            #pragma unroll
            for (int i2 = 0; i2 < 16; ++i2) {
                int col = bnh + i2;
                Bs[col][bk ^ (((col >> 4) & 3) << 3)] = (__bf16)src[i2];
            }
        }
        __syncthreads();

        bf16x8 af[4], bfr[4];
        #pragma unroll
        for (int f = 0; f < 4; ++f)
            af[f] = *(const bf16x8*)&As[wm + f * 16 + lo][hi << 3];
        #pragma unroll
        for (int f = 0; f < 4; ++f) {
            const int cswz = (((wn >> 4) + f) & 3) << 3;
            bfr[f] = *(const bf16x8*)&Bs[wn + f * 16 + lo][(hi << 3) ^ cswz];
        }
        #pragma unroll
        for (int fm = 0; fm < 4; ++fm)
            #pragma unroll
            for (int fn = 0; fn < 4; ++fn)
                acc[fm][fn] = __builtin_amdgcn_mfma_f32_16x16x32_bf16(af[fm], bfr[fn], acc[fm][fn], 0, 0, 0);
        __syncthreads();
    }

    #pragma unroll
    for (int fm = 0; fm < 4; ++fm) {
        const int64_t mrow = r0 + wm + fm * 16 + hi * 4;
        #pragma unroll
        for (int fn = 0; fn < 4; ++fn) {
            const int col = n0 + wn + fn * 16 + lo;
            const float bv = bias[col];
            #pragma unroll
            for (int r = 0; r < 4; ++r)
                out[(mrow + r) * 1024 + col] = acc[fm][fn][r] + bv;
        }
    }
}

// fast tanh: 1 - 2/(exp(2x)+1); saturates correctly for |x| large.
__device__ __forceinline__ float tanh_fast(float x) {
    float e = __builtin_amdgcn_exp2f(x * 2.885390082f);
    return 1.0f - 2.0f * __builtin_amdgcn_rcpf(e + 1.0f);
}

// ---------------- Phase 2: persistent recurrent scan ----------------
__global__ __launch_bounds__(512, 2) void rnn_scan(
    const float* __restrict__ W, float* __restrict__ out,
    unsigned int* hx, int* reg)
{
    __shared__ __align__(16) unsigned char A_lds[2][16 * 2048];  // dbuf 2x32KB
    __shared__ int s_role[2];

    const int tid = threadIdx.x;
    const int lane = tid & 63;
    const int wv  = tid >> 6;
    const int hi  = lane >> 4, lo = lane & 15;

    // ---- dynamic same-XCD ring formation ----
    if (tid == 0) {
        unsigned xcd;
        asm volatile("s_getreg_b32 %0, hwreg(20, 0, 32)" : "=s"(xcd));  // HW_REG_XCC_ID (m09)
        xcd &= 7;
        int rank = __hip_atomic_fetch_add(&reg[xcd], 1, __ATOMIC_RELAXED, __HIP_MEMORY_SCOPE_AGENT);
        __hip_atomic_fetch_add(&reg[8], 1, __ATOMIC_RELEASE, __HIP_MEMORY_SCOPE_AGENT);
        while (__hip_atomic_load(&reg[8], __ATOMIC_ACQUIRE, __HIP_MEMORY_SCOPE_AGENT) < SCAN_WGS)
            __builtin_amdgcn_s_sleep(8);
        int base = 0, ring = -1, slot = 0;
        for (int xx = 0; xx < 8; ++xx) {
            int cx = __hip_atomic_load(&reg[xx], __ATOMIC_RELAXED, __HIP_MEMORY_SCOPE_AGENT);
            int g = cx >> 3;
            int take = 4 - base; if (g < take) take = g;
            if (xx == (int)xcd) {
                int mygroup = rank >> 3;
                if (mygroup < take) { ring = base + mygroup; slot = rank & 7; }
            }
            base += take;
        }
        s_role[0] = ring; s_role[1] = slot;
    }
    __syncthreads();
    const int ig = s_role[0];       // ring -> batch rows 16*ig..+15
    const int jg = s_role[1];       // slot -> hidden cols 128*jg..+127
    if (ig < 0) return;             // unassigned WG exits

    // ---- one-time: Wh B-frags for this wave's 16 cols, ALL K, in registers ----
    const int col = jg * 128 + wv * 16 + lo;
    bf16x8 breg[32];
    {
        const float* wb = W + (int64_t)1024 * 1024 + col;
        #pragma unroll
        for (int kb = 0; kb < 32; ++kb) {
            const float* src = wb + (int64_t)(kb * 32 + hi * 8) * 1024;
            bf16x8 tf;
            #pragma unroll
            for (int j = 0; j < 8; ++j) tf[j] = (__bf16)src[(int64_t)j * 1024];
            breg[kb] = tf;
        }
    }

    // staging role: 16 rows x 32 threads/row, 16 u64 (32 cols) each
    const int srow = tid >> 5;
    const int c32  = tid & 31;
    const unsigned slab_byte = (unsigned)(((ig * 16 + srow) * 512 + c32 * 16) * 8);
    const unsigned swz_w  = (unsigned)((srow & 7) << 4);
    const unsigned kbyte0 = (unsigned)(c32 * 64);

    // compute role: A-frag read base
    const unsigned abase = (unsigned)(lo * 2048);
    const unsigned axor  = (unsigned)((lo & 7) << 4);

    const int64_t rstride = (int64_t)T_LEN * HID;
    float* pr0 = out + (int64_t)(ig * 16 + hi * 4) * rstride + col;
    const int wr0 = (ig * 16 + hi * 4) * 1024 + col;

    bool degraded = false;
    unsigned savedv[4] = {0, 0, 0, 0};
    int saved_slot = 0;

    for (int t = 0; t < T_LEN; ++t) {
        // XP prefetch (overlaps the spin)
        float xpv0 = pr0[(int64_t)t * HID];
        float xpv1 = pr0[(int64_t)t * HID + rstride];
        float xpv2 = pr0[(int64_t)t * HID + 2 * rstride];
        float xpv3 = pr0[(int64_t)t * HID + 3 * rstride];

        if (t > 0) {
            const unsigned exptag = (unsigned)t;
            const unsigned* sbase = hx + ((t - 1) & 1) * 65536;   // uniform -> SGPR pair
            u32x4 r0, r1, r2, r3, r4, r5, r6, r7;
            unsigned retries = 0;
            for (;;) {
                if (!degraded) {
                    asm volatile(
                        "global_load_dwordx4 %0, %8, %9 offset:0 sc0\n\t"
                        "global_load_dwordx4 %1, %8, %9 offset:16 sc0\n\t"
                        "global_load_dwordx4 %2, %8, %9 offset:32 sc0\n\t"
                        "global_load_dwordx4 %3, %8, %9 offset:48 sc0\n\t"
                        "global_load_dwordx4 %4, %8, %9 offset:64 sc0\n\t"
                        "global_load_dwordx4 %5, %8, %9 offset:80 sc0\n\t"
                        "global_load_dwordx4 %6, %8, %9 offset:96 sc0\n\t"
                        "global_load_dwordx4 %7, %8, %9 offset:112 sc0\n\t"
                        "s_waitcnt vmcnt(0)"
                        : "=&v"(r0), "=&v"(r1), "=&v"(r2), "=&v"(r3),
                          "=&v"(r4), "=&v"(r5), "=&v"(r6), "=&v"(r7)
                        : "v"(slab_byte), "s"(sbase));
                } else {
                    const u64* bp = (const u64*)(sbase + slab_byte / 4);
                    u64 q[16];
                    #pragma unroll
                    for (int j = 0; j < 16; ++j)
                        q[j] = __hip_atomic_load(bp + j, __ATOMIC_RELAXED, __HIP_MEMORY_SCOPE_AGENT);
                    r0 = u32x4{(unsigned)q[0], (unsigned)(q[0] >> 32), (unsigned)q[1], (unsigned)(q[1] >> 32)};
                    r1 = u32x4{(unsigned)q[2], (unsigned)(q[2] >> 32), (unsigned)q[3], (unsigned)(q[3] >> 32)};
                    r2 = u32x4{(unsigned)q[4], (unsigned)(q[4] >> 32), (unsigned)q[5], (unsigned)(q[5] >> 32)};
                    r3 = u32x4{(unsigned)q[6], (unsigned)(q[6] >> 32), (unsigned)q[7], (unsigned)(q[7] >> 32)};
                    r4 = u32x4{(unsigned)q[8], (unsigned)(q[8] >> 32), (unsigned)q[9], (unsigned)(q[9] >> 32)};
                    r5 = u32x4{(unsigned)q[10], (unsigned)(q[10] >> 32), (unsigned)q[11], (unsigned)(q[11] >> 32)};
                    r6 = u32x4{(unsigned)q[12], (unsigned)(q[12] >> 32), (unsigned)q[13], (unsigned)(q[13] >> 32)};
                    r7 = u32x4{(unsigned)q[14], (unsigned)(q[14] >> 32), (unsigned)q[15], (unsigned)(q[15] >> 32)};
                }
                unsigned badm = 0;
                #define CKTAG(rr) badm |= ((rr.x >> 16) ^ exptag) | ((rr.y >> 16) ^ exptag) \
                                        | ((rr.z >> 16) ^ exptag) | ((rr.w >> 16) ^ exptag)
                CKTAG(r0); CKTAG(r1); CKTAG(r2); CKTAG(r3);
                CKTAG(r4); CKTAG(r5); CKTAG(r6); CKTAG(r7);
                #undef CKTAG
                if (!badm) break;
                if (++retries > (1u << 17) && !degraded) {
                    // liveness fallback: same-XCD L2 path not observing -> go IF-coherent
                    degraded = true;
                    #pragma unroll
                    for (int rr = 0; rr < 4; ++rr)
                        __hip_atomic_store(hx + saved_slot * 65536 + wr0 + rr * 1024, savedv[rr],
                                           __ATOMIC_RELAXED, __HIP_MEMORY_SCOPE_AGENT);
                }
                if (degraded) { __builtin_amdgcn_s_sleep(16); }
                else          { __builtin_amdgcn_s_sleep(1);  }
            }

            // unpack {tag|bf16}x2 -> packed bf16x2 dwords, write swizzled LDS (dbuf t&1)
            unsigned dwp[16];
            dwp[0]  = __builtin_amdgcn_perm(r0.y, r0.x, 0x05040100u);
            dwp[1]  = __builtin_amdgcn_perm(r0.w, r0.z, 0x05040100u);
            dwp[2]  = __builtin_amdgcn_perm(r1.y, r1.x, 0x05040100u);
            dwp[3]  = __builtin_amdgcn_perm(r1.w, r1.z, 0x05040100u);
            dwp[4]  = __builtin_amdgcn_perm(r2.y, r2.x, 0x05040100u);
            dwp[5]  = __builtin_amdgcn_perm(r2.w, r2.z, 0x05040100u);
            dwp[6]  = __builtin_amdgcn_perm(r3.y, r3.x, 0x05040100u);
            dwp[7]  = __builtin_amdgcn_perm(r3.w, r3.z, 0x05040100u);
            dwp[8]  = __builtin_amdgcn_perm(r4.y, r4.x, 0x05040100u);
            dwp[9]  = __builtin_amdgcn_perm(r4.w, r4.z, 0x05040100u);
            dwp[10] = __builtin_amdgcn_perm(r5.y, r5.x, 0x05040100u);
            dwp[11] = __builtin_amdgcn_perm(r5.w, r5.z, 0x05040100u);
            dwp[12] = __builtin_amdgcn_perm(r6.y, r6.x, 0x05040100u);
            dwp[13] = __builtin_amdgcn_perm(r6.w, r6.z, 0x05040100u);
            dwp[14] = __builtin_amdgcn_perm(r7.y, r7.x, 0x05040100u);
            dwp[15] = __builtin_amdgcn_perm(r7.w, r7.z, 0x05040100u);
            unsigned char* Ab = &A_lds[t & 1][0];
            #pragma unroll
            for (int i = 0; i < 4; ++i) {
                f32x4 v = { __builtin_bit_cast(float, dwp[4 * i]),
                            __builtin_bit_cast(float, dwp[4 * i + 1]),
                            __builtin_bit_cast(float, dwp[4 * i + 2]),
                            __builtin_bit_cast(float, dwp[4 * i + 3]) };
                *(f32x4*)(Ab + srow * 2048 + ((kbyte0 + 16 * i) ^ swz_w)) = v;
            }
        }

        __syncthreads();   // A_lds[t&1] ready (also orders vs prior-step reads)

        f32x4 accs = {0.f, 0.f, 0.f, 0.f};
        if (t > 0) {
            const unsigned char* Ab = &A_lds[t & 1][0];
            f32x4 acc0 = {0.f, 0.f, 0.f, 0.f}, acc1 = {0.f, 0.f, 0.f, 0.f};
            #pragma unroll
            for (int kb = 0; kb < 32; kb += 2) {
                bf16x8 a0 = *(const bf16x8*)(Ab + abase + (((unsigned)(kb * 64) + hi * 16) ^ axor));
                bf16x8 a1 = *(const bf16x8*)(Ab + abase + (((unsigned)((kb + 1) * 64) + hi * 16) ^ axor));
                acc0 = __builtin_amdgcn_mfma_f32_16x16x32_bf16(a0, breg[kb],     acc0, 0, 0, 0);
                acc1 = __builtin_amdgcn_mfma_f32_16x16x32_bf16(a1, breg[kb + 1], acc1, 0, 0, 0);
            }
            accs = acc0 + acc1;
        }

        float h0 = tanh_fast(xpv0 + accs[0]);
        float h1 = tanh_fast(xpv1 + accs[1]);
        float h2 = tanh_fast(xpv2 + accs[2]);
        float h3 = tanh_fast(xpv3 + accs[3]);

        // exchange stores first (critical path): plain stores land in shared L2
        const unsigned tagw = (unsigned)(t + 1) << 16;
        unsigned v0 = tagw | __builtin_bit_cast(unsigned short, (__bf16)h0);
        unsigned v1 = tagw | __builtin_bit_cast(unsigned short, (__bf16)h1);
        unsigned v2 = tagw | __builtin_bit_cast(unsigned short, (__bf16)h2);
        unsigned v3 = tagw | __builtin_bit_cast(unsigned short, (__bf16)h3);
        volatile unsigned* hxs = hx + (t & 1) * 65536 + wr0;
        hxs[0] = v0; hxs[1024] = v1; hxs[2048] = v2; hxs[3072] = v3;
        if (degraded) {
            __hip_atomic_store(hx + (t & 1) * 65536 + wr0,        v0, __ATOMIC_RELAXED, __HIP_MEMORY_SCOPE_AGENT);
            __hip_atomic_store(hx + (t & 1) * 65536 + wr0 + 1024, v1, __ATOMIC_RELAXED, __HIP_MEMORY_SCOPE_AGENT);
            __hip_atomic_store(hx + (t & 1) * 65536 + wr0 + 2048, v2, __ATOMIC_RELAXED, __HIP_MEMORY_SCOPE_AGENT);
            __hip_atomic_store(hx + (t & 1) * 65536 + wr0 + 3072, v3, __ATOMIC_RELAXED, __HIP_MEMORY_SCOPE_AGENT);
        }
        savedv[0] = v0; savedv[1] = v1; savedv[2] = v2; savedv[3] = v3;
        saved_slot = t & 1;

        pr0[(int64_t)t * HID]               = h0;   // fp32 outputs
        pr0[(int64_t)t * HID + rstride]     = h1;
        pr0[(int64_t)t * HID + 2 * rstride] = h2;
        pr0[(int64_t)t * HID + 3 * rstride] = h3;
    }
}

extern "C" void kernel_launch(void* const* d_in, const int* in_sizes, int n_in,
                              void* d_out, int out_size, void* d_ws, size_t ws_size,
                              hipStream_t stream)
{
    const float* x    = (const float*)d_in[0];   // [64,1024,1024]
    const float* W    = (const float*)d_in[1];   // [2048,1024]
    const float* bias = (const float*)d_in[2];   // [1024]
    float* out = (float*)d_out;                  // [64,1024,1024]

    unsigned int* hx  = (unsigned int*)d_ws;                    // 2 slots x 64x1024 u32 = 512 KB
    int*          reg = (int*)((char*)d_ws + 524288);           // xcd_cnt[8] + done

    (void)hipMemsetAsync(d_ws, 0, 524288 + 64, stream);         // tags + registration
    xproj_gemm<<<dim3(4096), dim3(256), 0, stream>>>(x, W, bias, out);
    rnn_scan<<<dim3(SCAN_WGS), dim3(512), 0, stream>>>(W, out, hx, reg);
}